// Round 21
// baseline (80.626 us; speedup 1.0000x reference)
//
#include <hip/hip_runtime.h>

// ---------------------------------------------------------------------------
//  x (10,3,250,250)
//  conv1 5x5 s2 p1 + relu + pool -> p1 (10,6,123,123)
//      convpool1: 4 pool rows x 31 cols, 256 thr, grid (10,31,4) [R15 best]
//  conv2 3x3 s2 p1 + relu + pool -> p2, batch stride 55816
//      convpool2: 2 pool rows x 16 cols, 128 thr, grid (10,31,4) [R15 best]
//  fc1 (120,55815) split-K partials (float4 act, chunk 768) + counter reset
//  fcA: fc1-reduce (2-thread/row split chain) + fc2 relu + fc3 -> h3 (10,)
//  clsBC: qnn (redundant/block) + RBF partials + LAST-block fixed-order sum
//      -> out  [5 launches total]
//
//  MEASURED NOTES:
//   - conv weights stay in GLOBAL (uniform index -> s_load). LDS-staging
//     them: VGPR 52->168, occ 20->9.6% (R5).
//   - hipLaunchCooperativeKernel: 431us whole-net (R10); +28us even for a
//     64-blk tail (R17). NEVER coop here.
//   - REDUNDANT fcA per block (R18 tail3): 62us/dispatch. Never replicate
//     the fc1-reduce; partition it.
//   - Tail cost measured by differencing R18/R15: fcA+clsB+clsC ~= 23us.
//   - BLOCK-PARALLELISM lever: conv1/conv2 620->1240 = -2.8/-3.0us
//     (R14/R15); conv1 1240->2480 = +4.1us (R16) -> saturated.
//   - fc1 chunk 768 best (R6/R11/R12 sweep).
//   - last-block atomic + threadfence + volatile fixed-order sum validated
//     deterministic on this chip (R18, absmax 0.0).
// ---------------------------------------------------------------------------

#define ACT_STRIDE 55816   // 55815 padded to multiple of 8

// ===== conv1 + relu + pool fused. grid (10, 31, 4), block 256 =====
__global__ __launch_bounds__(256) void convpool1_k(
    const float* __restrict__ x, const float* __restrict__ w,
    const float* __restrict__ bias, float* __restrict__ out /*(10,6,123,123)*/) {
    const int b   = blockIdx.x;
    const int py0 = blockIdx.y * 4;
    const int px0 = blockIdx.z * 31;
    const int n_py = (123 - py0) < 4 ? (123 - py0) : 4;
    const int n_oy = n_py + 1;
    const int iy0 = 2 * py0 - 1;
    const int ix0 = 2 * px0 - 1;

    __shared__ float sx[3][13][68];
    __shared__ float so[6][5][32];

    const int tid = threadIdx.x;

    for (int j = tid; j < 3 * 13 * 67; j += 256) {
        int c  = j % 67;
        int r  = (j / 67) % 13;
        int ic = j / (67 * 13);
        int ix = ix0 + c, iy = iy0 + r;
        float v = 0.f;
        if ((unsigned)ix < 250u && (unsigned)iy < 250u)
            v = x[((size_t)(b * 3 + ic) * 250 + iy) * 250 + ix];
        sx[ic][r][c] = v;
    }
    __syncthreads();

    for (int p = tid; p < n_oy * 32; p += 256) {
        int oxl = p & 31;
        int oyl = p >> 5;
        if (px0 + oxl < 124) {
            float acc[6];
            #pragma unroll
            for (int o = 0; o < 6; ++o) acc[o] = bias[o];
            #pragma unroll
            for (int ic = 0; ic < 3; ++ic) {
                #pragma unroll
                for (int ky = 0; ky < 5; ++ky) {
                    const float* xr = &sx[ic][2 * oyl + ky][2 * oxl];
                    #pragma unroll
                    for (int kx = 0; kx < 5; ++kx) {
                        float xv = xr[kx];
                        #pragma unroll
                        for (int o = 0; o < 6; ++o)
                            acc[o] += w[((o * 3 + ic) * 5 + ky) * 5 + kx] * xv;
                    }
                }
            }
            #pragma unroll
            for (int o = 0; o < 6; ++o) so[o][oyl][oxl] = fmaxf(acc[o], 0.f);
        }
    }
    __syncthreads();

    for (int j = tid; j < 6 * 4 * 31; j += 256) {
        int pxl = j % 31;
        int pyl = (j / 31) & 3;
        int oc  = j / 124;
        int px = px0 + pxl, py = py0 + pyl;
        if (pyl < n_py && px < 123) {
            float v = fmaxf(fmaxf(so[oc][pyl][pxl],     so[oc][pyl][pxl + 1]),
                            fmaxf(so[oc][pyl + 1][pxl], so[oc][pyl + 1][pxl + 1]));
            out[((size_t)(b * 6 + oc) * 123 + py) * 123 + px] = v;
        }
    }
}

// ===== conv2 + relu + pool fused. grid (10, 31, 4), block 128 =====
__global__ __launch_bounds__(128) void convpool2_k(
    const float* __restrict__ in /*(10,6,123,123)*/, const float* __restrict__ w,
    const float* __restrict__ bias, float* __restrict__ out /*padded (10,55816)*/) {
    const int b   = blockIdx.x;
    const int py0 = blockIdx.y * 2;
    const int px0 = blockIdx.z * 16;
    const int n_py = (61 - py0) < 2 ? (61 - py0) : 2;
    const int n_oy = n_py + 1;
    const int iy0 = 2 * py0 - 1;
    const int ix0 = 2 * px0 - 1;

    __shared__ float sx[6][7][36];
    __shared__ float so[15][3][20];

    const int tid = threadIdx.x;

    for (int j = tid; j < 6 * 7 * 35; j += 128) {
        int col = j % 35;
        int r   = (j / 35) % 7;
        int ic  = j / (35 * 7);
        int ix = ix0 + col, iy = iy0 + r;
        float v = 0.f;
        if ((unsigned)ix < 123u && (unsigned)iy < 123u)
            v = in[((size_t)(b * 6 + ic) * 123 + iy) * 123 + ix];
        sx[ic][r][col] = v;
    }
    __syncthreads();

    for (int p = tid; p < n_oy * 17; p += 128) {
        int oxl = p % 17;
        int oyl = p / 17;
        if (px0 + oxl < 62) {
            float acc[15];
            #pragma unroll
            for (int o = 0; o < 15; ++o) acc[o] = bias[o];
            #pragma unroll
            for (int ic = 0; ic < 6; ++ic) {
                #pragma unroll
                for (int ky = 0; ky < 3; ++ky) {
                    const float* xr = &sx[ic][2 * oyl + ky][2 * oxl];
                    #pragma unroll
                    for (int kx = 0; kx < 3; ++kx) {
                        float xv = xr[kx];
                        #pragma unroll
                        for (int o = 0; o < 15; ++o)
                            acc[o] += w[((o * 6 + ic) * 3 + ky) * 3 + kx] * xv;
                    }
                }
            }
            #pragma unroll
            for (int o = 0; o < 15; ++o) so[o][oyl][oxl] = fmaxf(acc[o], 0.f);
        }
    }
    __syncthreads();

    for (int j = tid; j < 15 * 2 * 16; j += 128) {
        int pxl = j & 15;
        int pyl = (j >> 4) & 1;
        int oc  = j >> 5;
        int px = px0 + pxl, py = py0 + pyl;
        if (pyl < n_py && px < 61) {
            float v = fmaxf(fmaxf(so[oc][pyl][pxl],     so[oc][pyl][pxl + 1]),
                            fmaxf(so[oc][pyl + 1][pxl], so[oc][pyl + 1][pxl + 1]));
            out[(size_t)b * ACT_STRIDE + ((size_t)oc * 61 + py) * 61 + px] = v;
        }
    }
}

// ================= fc1: split-K partials =================
#define FC1_K      55815
#define FC1_CHUNK  768
#define FC1_NC     73
#define FC1_RT     15

// grid (15, 73), block 256. Also resets the clsBC block counter.
__global__ __launch_bounds__(256) void fc1_partial_k(
    const float* __restrict__ act /*(10, ACT_STRIDE)*/,
    const float* __restrict__ w   /*(120, 55815)*/,
    float* __restrict__ partials  /*(73,120,10)*/,
    int* __restrict__ counter) {
    if (blockIdx.x == 0 && blockIdx.y == 0 && threadIdx.x == 0) *counter = 0;
    int rt  = blockIdx.x;
    int c   = blockIdx.y;
    int tid = threadIdx.x;
    int wave = tid >> 6, lane = tid & 63;
    int k0 = c * FC1_CHUNK;
    int k1 = k0 + FC1_CHUNK; if (k1 > FC1_K) k1 = FC1_K;
    int r0 = rt * 8 + wave * 2;
    const float* w0 = w + (size_t)r0 * FC1_K;
    const float* w1 = w + (size_t)(r0 + 1) * FC1_K;

    float acc0[10], acc1[10];
    #pragma unroll
    for (int b = 0; b < 10; ++b) { acc0[b] = 0.f; acc1[b] = 0.f; }

    for (int k = k0 + lane * 4; k < k1; k += 256) {
        if (k + 4 <= k1) {
            float4 a4[10];
            #pragma unroll
            for (int b = 0; b < 10; ++b)
                a4[b] = *reinterpret_cast<const float4*>(act + (size_t)b * ACT_STRIDE + k);
            float w00 = w0[k], w01 = w0[k + 1], w02 = w0[k + 2], w03 = w0[k + 3];
            float w10 = w1[k], w11 = w1[k + 1], w12 = w1[k + 2], w13 = w1[k + 3];
            #pragma unroll
            for (int b = 0; b < 10; ++b) {
                acc0[b] += w00 * a4[b].x + w01 * a4[b].y + w02 * a4[b].z + w03 * a4[b].w;
                acc1[b] += w10 * a4[b].x + w11 * a4[b].y + w12 * a4[b].z + w13 * a4[b].w;
            }
        } else {
            for (int j = 0; j < k1 - k; ++j) {
                float wv0 = w0[k + j], wv1 = w1[k + j];
                #pragma unroll
                for (int b = 0; b < 10; ++b) {
                    float av = act[(size_t)b * ACT_STRIDE + k + j];
                    acc0[b] += wv0 * av;
                    acc1[b] += wv1 * av;
                }
            }
        }
    }
    #pragma unroll
    for (int b = 0; b < 10; ++b) {
        float v0 = acc0[b], v1 = acc1[b];
        for (int off = 32; off > 0; off >>= 1) {
            v0 += __shfl_down(v0, off);
            v1 += __shfl_down(v1, off);
        }
        if (lane == 0) {
            size_t base = ((size_t)c * 120 + r0) * 10;
            partials[base + b]      = v0;
            partials[base + 10 + b] = v1;
        }
    }
}

// ===== fcA: fc1-reduce (split chain) + fc2 + fc3. grid 10 x 256 =====
__global__ __launch_bounds__(256) void fcA_k(
    const float* __restrict__ part /*(73,120,10)*/, const float* __restrict__ fc1_b,
    const float* __restrict__ fc2_w, const float* __restrict__ fc2_b,
    const float* __restrict__ fc3_w, const float* __restrict__ fc3_b,
    float* __restrict__ h3 /*(10,)*/) {
    const int b = blockIdx.x;
    const int tid = threadIdx.x;
    __shared__ float s_red[240];
    __shared__ float s_act[120];
    __shared__ float s_fc2[84];

    // 2 threads per row: halves of the 73-chunk sum (37 + 36)
    if (tid < 240) {
        int row  = tid >> 1;
        int half = tid & 1;
        int c0 = half ? 37 : 0;
        int c1 = half ? 73 : 37;
        float s = 0.f;
        #pragma unroll 8
        for (int c = c0; c < c1; ++c) s += part[((size_t)c * 120 + row) * 10 + b];
        s_red[tid] = s;
    }
    __syncthreads();
    if (tid < 120)
        s_act[tid] = fmaxf(s_red[2 * tid] + s_red[2 * tid + 1] + fc1_b[tid], 0.f);
    __syncthreads();
    if (tid < 84) {
        float acc = fc2_b[tid];
        #pragma unroll 4
        for (int k = 0; k < 120; ++k) acc += s_act[k] * fc2_w[tid * 120 + k];
        s_fc2[tid] = fmaxf(acc, 0.f);
    }
    __syncthreads();
    if (tid < 64) {
        float v = s_fc2[tid] * fc3_w[tid];
        if (tid < 20) v += s_fc2[tid + 64] * fc3_w[tid + 64];
        for (int off = 32; off > 0; off >>= 1) v += __shfl_down(v, off);
        if (tid == 0) h3[b] = v + fc3_b[0];
    }
}

// ===== clsBC: qnn (redundant) + RBF partials + last-block final sum =====
// 64 blocks x 128 threads.
__global__ __launch_bounds__(128) void clsBC_k(
    const float* __restrict__ h3 /*(10,)*/,
    const float* __restrict__ qw1, const float* __restrict__ qw2,
    const float* __restrict__ ts /*(8192,5)*/, const float* __restrict__ kw /*(2,8192)*/,
    const float* __restrict__ kb,
    float* __restrict__ partials /*(64,2)*/, int* __restrict__ counter,
    float* __restrict__ outp /*(2,)*/) {
    const int bid = blockIdx.x;
    const int tid = threadIdx.x;
    __shared__ float s_h3[10], s_s1[20], s_fs[5];
    __shared__ float l0[2], l1[2];
    __shared__ int s_old;

    if (tid < 10) s_h3[tid] = h3[tid];
    __syncthreads();
    if (tid < 20) {
        float acc = 0.f;
        for (int b = 0; b < 10; ++b) acc += qw1[tid * 10 + b] * s_h3[b];
        s_s1[tid] = tanhf(acc);
    }
    __syncthreads();
    if (tid < 5) {
        float acc = 0.f;
        for (int j = 0; j < 20; ++j) acc += qw2[tid * 20 + j] * s_s1[j];
        s_fs[tid] = tanhf(acc);
    }
    __syncthreads();

    float f0 = s_fs[0], f1 = s_fs[1], f2 = s_fs[2], f3 = s_fs[3], f4 = s_fs[4];
    int n = bid * 128 + tid;
    const float* t = ts + (size_t)n * 5;
    float d0 = f0 - t[0], d1 = f1 - t[1], d2 = f2 - t[2], d3 = f3 - t[3], d4 = f4 - t[4];
    float Kv = expf(-(d0 * d0 + d1 * d1 + d2 * d2 + d3 * d3 + d4 * d4));
    float a0 = Kv * kw[n];
    float a1 = Kv * kw[8192 + n];
    for (int off = 32; off > 0; off >>= 1) {
        a0 += __shfl_down(a0, off);
        a1 += __shfl_down(a1, off);
    }
    int wave = tid >> 6, lane = tid & 63;
    if (lane == 0) { l0[wave] = a0; l1[wave] = a1; }
    __syncthreads();
    if (tid == 0) {
        partials[bid * 2 + 0] = l0[0] + l0[1];
        partials[bid * 2 + 1] = l1[0] + l1[1];
    }

    // last-finishing block sums in fixed order (deterministic)
    __threadfence();
    if (tid == 0) s_old = atomicAdd(counter, 1);
    __syncthreads();
    if (s_old == 63) {
        __threadfence();
        if (tid < 2) {
            volatile const float* vp = partials;
            float acc = kb[tid];
            for (int i = 0; i < 64; ++i) acc += vp[i * 2 + tid];
            outp[tid] = acc;
        }
    }
}

extern "C" void kernel_launch(void* const* d_in, const int* in_sizes, int n_in,
                              void* d_out, int out_size, void* d_ws, size_t ws_size,
                              hipStream_t stream) {
    const float* x        = (const float*)d_in[0];
    const float* conv1_w  = (const float*)d_in[1];
    const float* conv1_b  = (const float*)d_in[2];
    const float* conv2_w  = (const float*)d_in[3];
    const float* conv2_b  = (const float*)d_in[4];
    const float* fc1_w    = (const float*)d_in[5];
    const float* fc1_b    = (const float*)d_in[6];
    const float* fc2_w    = (const float*)d_in[7];
    const float* fc2_b    = (const float*)d_in[8];
    const float* fc3_w    = (const float*)d_in[9];
    const float* fc3_b    = (const float*)d_in[10];
    const float* qnn_w1   = (const float*)d_in[11];
    const float* qnn_w2   = (const float*)d_in[12];
    const float* tstates  = (const float*)d_in[13];
    const float* kcls_w   = (const float*)d_in[14];
    const float* kcls_b   = (const float*)d_in[15];

    float* ws = (float*)d_ws;
    float* p1       = ws;                  // 10*6*123*123 = 907740
    float* p2       = p1 + 907740;         // 10*ACT_STRIDE = 558160 (16B-aligned)
    float* fc1_part = p2 + 558160;         // 73*120*10 = 87600
    float* h3       = fc1_part + 87600;    // 16
    float* partials = h3 + 16;             // 128
    int*   counter  = (int*)(partials + 128);
    float* outp     = (float*)d_out;

    convpool1_k<<<dim3(10, 31, 4), 256, 0, stream>>>(x, conv1_w, conv1_b, p1);
    convpool2_k<<<dim3(10, 31, 4), 128, 0, stream>>>(p1, conv2_w, conv2_b, p2);
    fc1_partial_k<<<dim3(FC1_RT, FC1_NC), 256, 0, stream>>>(p2, fc1_w, fc1_part, counter);
    fcA_k<<<10, 256, 0, stream>>>(fc1_part, fc1_b, fc2_w, fc2_b, fc3_w, fc3_b, h3);
    clsBC_k<<<64, 128, 0, stream>>>(h3, qnn_w1, qnn_w2, tstates, kcls_w, kcls_b,
                                    partials, counter, outp);
}

// Round 22
// 80.269 us; speedup vs baseline: 1.0045x; 1.0045x over previous
//
#include <hip/hip_runtime.h>

// ---------------------------------------------------------------------------
//  x (10,3,250,250)
//  conv1 5x5 s2 p1 + relu + pool -> p1 (10,6,123,123)
//      convpool1: 4 pool rows x 31 cols, 256 thr, grid (10,31,4) [R15 best]
//  conv2 3x3 s2 p1 + relu + pool -> p2, batch stride 55816
//      convpool2: 2 pool rows x 16 cols, 128 thr, grid (10,31,4) [R15 best]
//  fc1 (120,55815) split-K partials (float4 act, chunk 768) + counter reset
//  fcA: fc1-reduce (2-thread/row split chain) + fc2 relu + fc3 -> h3 (10,)
//  clsBC: qnn (redundant/block) + RBF partials + LAST-block fixed-order sum
//      -> out  [5 launches total]
//
//  MEASURED NOTES:
//   - conv weights stay in GLOBAL (uniform index -> s_load). LDS-staging
//     them: VGPR 52->168, occ 20->9.6% (R5).
//   - hipLaunchCooperativeKernel: 431us whole-net (R10); +28us even for a
//     64-blk tail (R17). NEVER coop here.
//   - REDUNDANT fcA per block (R18 tail3): 62us/dispatch. Never replicate
//     the fc1-reduce; partition it.
//   - Tail cost measured by differencing R18/R15: fcA+clsB+clsC ~= 23us.
//   - BLOCK-PARALLELISM lever: conv1/conv2 620->1240 = -2.8/-3.0us
//     (R14/R15); conv1 1240->2480 = +4.1us (R16) -> saturated.
//   - fc1 chunk 768 best (R6/R11/R12 sweep).
//   - last-block atomic + threadfence + volatile fixed-order sum validated
//     deterministic on this chip (R18, absmax 0.0).
// ---------------------------------------------------------------------------

#define ACT_STRIDE 55816   // 55815 padded to multiple of 8

// ===== conv1 + relu + pool fused. grid (10, 31, 4), block 256 =====
__global__ __launch_bounds__(256) void convpool1_k(
    const float* __restrict__ x, const float* __restrict__ w,
    const float* __restrict__ bias, float* __restrict__ out /*(10,6,123,123)*/) {
    const int b   = blockIdx.x;
    const int py0 = blockIdx.y * 4;
    const int px0 = blockIdx.z * 31;
    const int n_py = (123 - py0) < 4 ? (123 - py0) : 4;
    const int n_oy = n_py + 1;
    const int iy0 = 2 * py0 - 1;
    const int ix0 = 2 * px0 - 1;

    __shared__ float sx[3][13][68];
    __shared__ float so[6][5][32];

    const int tid = threadIdx.x;

    for (int j = tid; j < 3 * 13 * 67; j += 256) {
        int c  = j % 67;
        int r  = (j / 67) % 13;
        int ic = j / (67 * 13);
        int ix = ix0 + c, iy = iy0 + r;
        float v = 0.f;
        if ((unsigned)ix < 250u && (unsigned)iy < 250u)
            v = x[((size_t)(b * 3 + ic) * 250 + iy) * 250 + ix];
        sx[ic][r][c] = v;
    }
    __syncthreads();

    for (int p = tid; p < n_oy * 32; p += 256) {
        int oxl = p & 31;
        int oyl = p >> 5;
        if (px0 + oxl < 124) {
            float acc[6];
            #pragma unroll
            for (int o = 0; o < 6; ++o) acc[o] = bias[o];
            #pragma unroll
            for (int ic = 0; ic < 3; ++ic) {
                #pragma unroll
                for (int ky = 0; ky < 5; ++ky) {
                    const float* xr = &sx[ic][2 * oyl + ky][2 * oxl];
                    #pragma unroll
                    for (int kx = 0; kx < 5; ++kx) {
                        float xv = xr[kx];
                        #pragma unroll
                        for (int o = 0; o < 6; ++o)
                            acc[o] += w[((o * 3 + ic) * 5 + ky) * 5 + kx] * xv;
                    }
                }
            }
            #pragma unroll
            for (int o = 0; o < 6; ++o) so[o][oyl][oxl] = fmaxf(acc[o], 0.f);
        }
    }
    __syncthreads();

    for (int j = tid; j < 6 * 4 * 31; j += 256) {
        int pxl = j % 31;
        int pyl = (j / 31) & 3;
        int oc  = j / 124;
        int px = px0 + pxl, py = py0 + pyl;
        if (pyl < n_py && px < 123) {
            float v = fmaxf(fmaxf(so[oc][pyl][pxl],     so[oc][pyl][pxl + 1]),
                            fmaxf(so[oc][pyl + 1][pxl], so[oc][pyl + 1][pxl + 1]));
            out[((size_t)(b * 6 + oc) * 123 + py) * 123 + px] = v;
        }
    }
}

// ===== conv2 + relu + pool fused. grid (10, 31, 4), block 128 =====
__global__ __launch_bounds__(128) void convpool2_k(
    const float* __restrict__ in /*(10,6,123,123)*/, const float* __restrict__ w,
    const float* __restrict__ bias, float* __restrict__ out /*padded (10,55816)*/) {
    const int b   = blockIdx.x;
    const int py0 = blockIdx.y * 2;
    const int px0 = blockIdx.z * 16;
    const int n_py = (61 - py0) < 2 ? (61 - py0) : 2;
    const int n_oy = n_py + 1;
    const int iy0 = 2 * py0 - 1;
    const int ix0 = 2 * px0 - 1;

    __shared__ float sx[6][7][36];
    __shared__ float so[15][3][20];

    const int tid = threadIdx.x;

    for (int j = tid; j < 6 * 7 * 35; j += 128) {
        int col = j % 35;
        int r   = (j / 35) % 7;
        int ic  = j / (35 * 7);
        int ix = ix0 + col, iy = iy0 + r;
        float v = 0.f;
        if ((unsigned)ix < 123u && (unsigned)iy < 123u)
            v = in[((size_t)(b * 6 + ic) * 123 + iy) * 123 + ix];
        sx[ic][r][col] = v;
    }
    __syncthreads();

    for (int p = tid; p < n_oy * 17; p += 128) {
        int oxl = p % 17;
        int oyl = p / 17;
        if (px0 + oxl < 62) {
            float acc[15];
            #pragma unroll
            for (int o = 0; o < 15; ++o) acc[o] = bias[o];
            #pragma unroll
            for (int ic = 0; ic < 6; ++ic) {
                #pragma unroll
                for (int ky = 0; ky < 3; ++ky) {
                    const float* xr = &sx[ic][2 * oyl + ky][2 * oxl];
                    #pragma unroll
                    for (int kx = 0; kx < 3; ++kx) {
                        float xv = xr[kx];
                        #pragma unroll
                        for (int o = 0; o < 15; ++o)
                            acc[o] += w[((o * 6 + ic) * 3 + ky) * 3 + kx] * xv;
                    }
                }
            }
            #pragma unroll
            for (int o = 0; o < 15; ++o) so[o][oyl][oxl] = fmaxf(acc[o], 0.f);
        }
    }
    __syncthreads();

    for (int j = tid; j < 15 * 2 * 16; j += 128) {
        int pxl = j & 15;
        int pyl = (j >> 4) & 1;
        int oc  = j >> 5;
        int px = px0 + pxl, py = py0 + pyl;
        if (pyl < n_py && px < 61) {
            float v = fmaxf(fmaxf(so[oc][pyl][pxl],     so[oc][pyl][pxl + 1]),
                            fmaxf(so[oc][pyl + 1][pxl], so[oc][pyl + 1][pxl + 1]));
            out[(size_t)b * ACT_STRIDE + ((size_t)oc * 61 + py) * 61 + px] = v;
        }
    }
}

// ================= fc1: split-K partials =================
#define FC1_K      55815
#define FC1_CHUNK  768
#define FC1_NC     73
#define FC1_RT     15

// grid (15, 73), block 256. Also resets the clsBC block counter.
__global__ __launch_bounds__(256) void fc1_partial_k(
    const float* __restrict__ act /*(10, ACT_STRIDE)*/,
    const float* __restrict__ w   /*(120, 55815)*/,
    float* __restrict__ partials  /*(73,120,10)*/,
    int* __restrict__ counter) {
    if (blockIdx.x == 0 && blockIdx.y == 0 && threadIdx.x == 0) *counter = 0;
    int rt  = blockIdx.x;
    int c   = blockIdx.y;
    int tid = threadIdx.x;
    int wave = tid >> 6, lane = tid & 63;
    int k0 = c * FC1_CHUNK;
    int k1 = k0 + FC1_CHUNK; if (k1 > FC1_K) k1 = FC1_K;
    int r0 = rt * 8 + wave * 2;
    const float* w0 = w + (size_t)r0 * FC1_K;
    const float* w1 = w + (size_t)(r0 + 1) * FC1_K;

    float acc0[10], acc1[10];
    #pragma unroll
    for (int b = 0; b < 10; ++b) { acc0[b] = 0.f; acc1[b] = 0.f; }

    for (int k = k0 + lane * 4; k < k1; k += 256) {
        if (k + 4 <= k1) {
            float4 a4[10];
            #pragma unroll
            for (int b = 0; b < 10; ++b)
                a4[b] = *reinterpret_cast<const float4*>(act + (size_t)b * ACT_STRIDE + k);
            float w00 = w0[k], w01 = w0[k + 1], w02 = w0[k + 2], w03 = w0[k + 3];
            float w10 = w1[k], w11 = w1[k + 1], w12 = w1[k + 2], w13 = w1[k + 3];
            #pragma unroll
            for (int b = 0; b < 10; ++b) {
                acc0[b] += w00 * a4[b].x + w01 * a4[b].y + w02 * a4[b].z + w03 * a4[b].w;
                acc1[b] += w10 * a4[b].x + w11 * a4[b].y + w12 * a4[b].z + w13 * a4[b].w;
            }
        } else {
            for (int j = 0; j < k1 - k; ++j) {
                float wv0 = w0[k + j], wv1 = w1[k + j];
                #pragma unroll
                for (int b = 0; b < 10; ++b) {
                    float av = act[(size_t)b * ACT_STRIDE + k + j];
                    acc0[b] += wv0 * av;
                    acc1[b] += wv1 * av;
                }
            }
        }
    }
    #pragma unroll
    for (int b = 0; b < 10; ++b) {
        float v0 = acc0[b], v1 = acc1[b];
        for (int off = 32; off > 0; off >>= 1) {
            v0 += __shfl_down(v0, off);
            v1 += __shfl_down(v1, off);
        }
        if (lane == 0) {
            size_t base = ((size_t)c * 120 + r0) * 10;
            partials[base + b]      = v0;
            partials[base + 10 + b] = v1;
        }
    }
}

// ===== fcA: fc1-reduce (split chain) + fc2 + fc3. grid 10 x 256 =====
__global__ __launch_bounds__(256) void fcA_k(
    const float* __restrict__ part /*(73,120,10)*/, const float* __restrict__ fc1_b,
    const float* __restrict__ fc2_w, const float* __restrict__ fc2_b,
    const float* __restrict__ fc3_w, const float* __restrict__ fc3_b,
    float* __restrict__ h3 /*(10,)*/) {
    const int b = blockIdx.x;
    const int tid = threadIdx.x;
    __shared__ float s_red[240];
    __shared__ float s_act[120];
    __shared__ float s_fc2[84];

    // 2 threads per row: halves of the 73-chunk sum (37 + 36)
    if (tid < 240) {
        int row  = tid >> 1;
        int half = tid & 1;
        int c0 = half ? 37 : 0;
        int c1 = half ? 73 : 37;
        float s = 0.f;
        #pragma unroll 8
        for (int c = c0; c < c1; ++c) s += part[((size_t)c * 120 + row) * 10 + b];
        s_red[tid] = s;
    }
    __syncthreads();
    if (tid < 120)
        s_act[tid] = fmaxf(s_red[2 * tid] + s_red[2 * tid + 1] + fc1_b[tid], 0.f);
    __syncthreads();
    if (tid < 84) {
        float acc = fc2_b[tid];
        #pragma unroll 4
        for (int k = 0; k < 120; ++k) acc += s_act[k] * fc2_w[tid * 120 + k];
        s_fc2[tid] = fmaxf(acc, 0.f);
    }
    __syncthreads();
    if (tid < 64) {
        float v = s_fc2[tid] * fc3_w[tid];
        if (tid < 20) v += s_fc2[tid + 64] * fc3_w[tid + 64];
        for (int off = 32; off > 0; off >>= 1) v += __shfl_down(v, off);
        if (tid == 0) h3[b] = v + fc3_b[0];
    }
}

// ===== clsBC: qnn (redundant) + RBF partials + last-block final sum =====
// 64 blocks x 128 threads.
__global__ __launch_bounds__(128) void clsBC_k(
    const float* __restrict__ h3 /*(10,)*/,
    const float* __restrict__ qw1, const float* __restrict__ qw2,
    const float* __restrict__ ts /*(8192,5)*/, const float* __restrict__ kw /*(2,8192)*/,
    const float* __restrict__ kb,
    float* __restrict__ partials /*(64,2)*/, int* __restrict__ counter,
    float* __restrict__ outp /*(2,)*/) {
    const int bid = blockIdx.x;
    const int tid = threadIdx.x;
    __shared__ float s_h3[10], s_s1[20], s_fs[5];
    __shared__ float l0[2], l1[2];
    __shared__ int s_old;

    if (tid < 10) s_h3[tid] = h3[tid];
    __syncthreads();
    if (tid < 20) {
        float acc = 0.f;
        for (int b = 0; b < 10; ++b) acc += qw1[tid * 10 + b] * s_h3[b];
        s_s1[tid] = tanhf(acc);
    }
    __syncthreads();
    if (tid < 5) {
        float acc = 0.f;
        for (int j = 0; j < 20; ++j) acc += qw2[tid * 20 + j] * s_s1[j];
        s_fs[tid] = tanhf(acc);
    }
    __syncthreads();

    float f0 = s_fs[0], f1 = s_fs[1], f2 = s_fs[2], f3 = s_fs[3], f4 = s_fs[4];
    int n = bid * 128 + tid;
    const float* t = ts + (size_t)n * 5;
    float d0 = f0 - t[0], d1 = f1 - t[1], d2 = f2 - t[2], d3 = f3 - t[3], d4 = f4 - t[4];
    float Kv = expf(-(d0 * d0 + d1 * d1 + d2 * d2 + d3 * d3 + d4 * d4));
    float a0 = Kv * kw[n];
    float a1 = Kv * kw[8192 + n];
    for (int off = 32; off > 0; off >>= 1) {
        a0 += __shfl_down(a0, off);
        a1 += __shfl_down(a1, off);
    }
    int wave = tid >> 6, lane = tid & 63;
    if (lane == 0) { l0[wave] = a0; l1[wave] = a1; }
    __syncthreads();
    if (tid == 0) {
        partials[bid * 2 + 0] = l0[0] + l0[1];
        partials[bid * 2 + 1] = l1[0] + l1[1];
    }

    // last-finishing block sums in fixed order (deterministic)
    __threadfence();
    if (tid == 0) s_old = atomicAdd(counter, 1);
    __syncthreads();
    if (s_old == 63) {
        __threadfence();
        if (tid < 2) {
            volatile const float* vp = partials;
            float acc = kb[tid];
            for (int i = 0; i < 64; ++i) acc += vp[i * 2 + tid];
            outp[tid] = acc;
        }
    }
}

extern "C" void kernel_launch(void* const* d_in, const int* in_sizes, int n_in,
                              void* d_out, int out_size, void* d_ws, size_t ws_size,
                              hipStream_t stream) {
    const float* x        = (const float*)d_in[0];
    const float* conv1_w  = (const float*)d_in[1];
    const float* conv1_b  = (const float*)d_in[2];
    const float* conv2_w  = (const float*)d_in[3];
    const float* conv2_b  = (const float*)d_in[4];
    const float* fc1_w    = (const float*)d_in[5];
    const float* fc1_b    = (const float*)d_in[6];
    const float* fc2_w    = (const float*)d_in[7];
    const float* fc2_b    = (const float*)d_in[8];
    const float* fc3_w    = (const float*)d_in[9];
    const float* fc3_b    = (const float*)d_in[10];
    const float* qnn_w1   = (const float*)d_in[11];
    const float* qnn_w2   = (const float*)d_in[12];
    const float* tstates  = (const float*)d_in[13];
    const float* kcls_w   = (const float*)d_in[14];
    const float* kcls_b   = (const float*)d_in[15];

    float* ws = (float*)d_ws;
    float* p1       = ws;                  // 10*6*123*123 = 907740
    float* p2       = p1 + 907740;         // 10*ACT_STRIDE = 558160 (16B-aligned)
    float* fc1_part = p2 + 558160;         // 73*120*10 = 87600
    float* h3       = fc1_part + 87600;    // 16
    float* partials = h3 + 16;             // 128
    int*   counter  = (int*)(partials + 128);
    float* outp     = (float*)d_out;

    convpool1_k<<<dim3(10, 31, 4), 256, 0, stream>>>(x, conv1_w, conv1_b, p1);
    convpool2_k<<<dim3(10, 31, 4), 128, 0, stream>>>(p1, conv2_w, conv2_b, p2);
    fc1_partial_k<<<dim3(FC1_RT, FC1_NC), 256, 0, stream>>>(p2, fc1_w, fc1_part, counter);
    fcA_k<<<10, 256, 0, stream>>>(fc1_part, fc1_b, fc2_w, fc2_b, fc3_w, fc3_b, h3);
    clsBC_k<<<64, 128, 0, stream>>>(h3, qnn_w1, qnn_w2, tstates, kcls_w, kcls_b,
                                    partials, counter, outp);
}

// Round 23
// 74.873 us; speedup vs baseline: 1.0768x; 1.0721x over previous
//
#include <hip/hip_runtime.h>

// ---------------------------------------------------------------------------
//  x (10,3,250,250)
//  conv1 5x5 s2 p1 + relu + pool 2x2 s1 -> p1 (10,6,123,123)
//      convpool1: 4 pool rows x 31 pool cols per block, 256 threads,
//      grid (10,31,4) = 1240 blocks, LDS 14.4 KB  [measured best, R15]
//  conv2 3x3 s2 p1 + relu + pool -> p2 (10,15,61,61), batch stride 55816
//      convpool2: 2 pool rows x 16 pool cols per block, 128 threads,
//      grid (10,31,4) = 1240 blocks, LDS ~10 KB   [measured best, R15]
//  fc1 (120,55815) split-K partials (float4 act loads, chunk 768)
//  fcA: fc1-reduce + fc2 relu + fc3 -> h3 (10,)
//  clsB: qnn tanh x2 (redundant per block) + RBF partials
//  clsC: final sum -> out (1,2)
//
//  MEASURED NOTES (22 rounds):
//   - conv weights stay in GLOBAL (uniform index -> s_load scalarization).
//     LDS-staging them: VGPR 52->168, occ 20->9.6% (R5).
//   - hipLaunchCooperativeKernel: 431us whole-net (R10); +28us for a 64-blk
//     tail with 2 grid.syncs (R17). Never coop in this harness.
//   - Redundant per-block fcA (R18): 62us/dispatch. Partition, don't replicate.
//   - Tail merge via atomic last-block (R22): 80.3us vs 75.1 split — neutral
//     to negative; launch boundaries are NOT the dominant residual.
//   - BLOCK-PARALLELISM lever: conv1 620->1240 = -2.8us (R14); conv2
//     620->1240 = -3.0us (R15); conv1 1240->2480 = +4.1us (R16) -> saturated.
//   - fc1 chunk 768 best (R6/R11/R12 sweep). Instruction-level conv variants
//     (deinterleave, reg-pool, wave-pool, win-batch): all within noise.
//   - Run-to-run noise ~ +/-3-5us; single-variable discipline required.
// ---------------------------------------------------------------------------

#define ACT_STRIDE 55816   // 55815 padded to multiple of 8

// ===== conv1 + relu + pool fused. grid (10, 31, 4), block 256 =====
__global__ __launch_bounds__(256) void convpool1_k(
    const float* __restrict__ x, const float* __restrict__ w,
    const float* __restrict__ bias, float* __restrict__ out /*(10,6,123,123)*/) {
    const int b   = blockIdx.x;
    const int py0 = blockIdx.y * 4;
    const int px0 = blockIdx.z * 31;
    const int n_py = (123 - py0) < 4 ? (123 - py0) : 4;
    const int n_oy = n_py + 1;
    const int iy0 = 2 * py0 - 1;
    const int ix0 = 2 * px0 - 1;

    __shared__ float sx[3][13][68];   // input tile (13 rows x 67 cols used)
    __shared__ float so[6][5][32];    // conv outputs

    const int tid = threadIdx.x;

    // ---- stage 3 x 13 x 67 (coalesced, zero-padded) ----
    for (int j = tid; j < 3 * 13 * 67; j += 256) {
        int c  = j % 67;
        int r  = (j / 67) % 13;
        int ic = j / (67 * 13);
        int ix = ix0 + c, iy = iy0 + r;
        float v = 0.f;
        if ((unsigned)ix < 250u && (unsigned)iy < 250u)
            v = x[((size_t)(b * 3 + ic) * 250 + iy) * 250 + ix];
        sx[ic][r][c] = v;
    }
    __syncthreads();

    // ---- conv: each thread one (oyl, oxl) for all 6 oc ----
    for (int p = tid; p < n_oy * 32; p += 256) {
        int oxl = p & 31;
        int oyl = p >> 5;
        if (px0 + oxl < 124) {
            float acc[6];
            #pragma unroll
            for (int o = 0; o < 6; ++o) acc[o] = bias[o];
            #pragma unroll
            for (int ic = 0; ic < 3; ++ic) {
                #pragma unroll
                for (int ky = 0; ky < 5; ++ky) {
                    const float* xr = &sx[ic][2 * oyl + ky][2 * oxl];
                    #pragma unroll
                    for (int kx = 0; kx < 5; ++kx) {
                        float xv = xr[kx];
                        #pragma unroll
                        for (int o = 0; o < 6; ++o)
                            acc[o] += w[((o * 3 + ic) * 5 + ky) * 5 + kx] * xv;
                    }
                }
            }
            #pragma unroll
            for (int o = 0; o < 6; ++o) so[o][oyl][oxl] = fmaxf(acc[o], 0.f);
        }
    }
    __syncthreads();

    // ---- pool 2x2 s1 + store: 6 oc x 4 py x 31 px jobs ----
    for (int j = tid; j < 6 * 4 * 31; j += 256) {
        int pxl = j % 31;
        int pyl = (j / 31) & 3;
        int oc  = j / 124;
        int px = px0 + pxl, py = py0 + pyl;
        if (pyl < n_py && px < 123) {
            float v = fmaxf(fmaxf(so[oc][pyl][pxl],     so[oc][pyl][pxl + 1]),
                            fmaxf(so[oc][pyl + 1][pxl], so[oc][pyl + 1][pxl + 1]));
            out[((size_t)(b * 6 + oc) * 123 + py) * 123 + px] = v;
        }
    }
}

// ===== conv2 + relu + pool fused. grid (10, 31, 4), block 128 =====
__global__ __launch_bounds__(128) void convpool2_k(
    const float* __restrict__ in /*(10,6,123,123)*/, const float* __restrict__ w,
    const float* __restrict__ bias, float* __restrict__ out /*padded (10,55816)*/) {
    const int b   = blockIdx.x;
    const int py0 = blockIdx.y * 2;
    const int px0 = blockIdx.z * 16;
    const int n_py = (61 - py0) < 2 ? (61 - py0) : 2;
    const int n_oy = n_py + 1;
    const int iy0 = 2 * py0 - 1;
    const int ix0 = 2 * px0 - 1;

    __shared__ float sx[6][7][36];    // 6 ic x 7 rows x 35 cols used
    __shared__ float so[15][3][20];   // 15 oc x 3 conv rows x 17 cols used

    const int tid = threadIdx.x;

    for (int j = tid; j < 6 * 7 * 35; j += 128) {
        int col = j % 35;
        int r   = (j / 35) % 7;
        int ic  = j / (35 * 7);
        int ix = ix0 + col, iy = iy0 + r;
        float v = 0.f;
        if ((unsigned)ix < 123u && (unsigned)iy < 123u)
            v = in[((size_t)(b * 6 + ic) * 123 + iy) * 123 + ix];
        sx[ic][r][col] = v;
    }
    __syncthreads();

    // conv positions: n_oy x 17 (<=51) -> one pass, all 15 oc per thread
    for (int p = tid; p < n_oy * 17; p += 128) {
        int oxl = p % 17;
        int oyl = p / 17;
        if (px0 + oxl < 62) {
            float acc[15];
            #pragma unroll
            for (int o = 0; o < 15; ++o) acc[o] = bias[o];
            #pragma unroll
            for (int ic = 0; ic < 6; ++ic) {
                #pragma unroll
                for (int ky = 0; ky < 3; ++ky) {
                    const float* xr = &sx[ic][2 * oyl + ky][2 * oxl];
                    #pragma unroll
                    for (int kx = 0; kx < 3; ++kx) {
                        float xv = xr[kx];
                        #pragma unroll
                        for (int o = 0; o < 15; ++o)
                            acc[o] += w[((o * 6 + ic) * 3 + ky) * 3 + kx] * xv;
                    }
                }
            }
            #pragma unroll
            for (int o = 0; o < 15; ++o) so[o][oyl][oxl] = fmaxf(acc[o], 0.f);
        }
    }
    __syncthreads();

    // pool: 15 oc x 2 py x 16 px = 480 jobs
    for (int j = tid; j < 15 * 2 * 16; j += 128) {
        int pxl = j & 15;
        int pyl = (j >> 4) & 1;
        int oc  = j >> 5;
        int px = px0 + pxl, py = py0 + pyl;
        if (pyl < n_py && px < 61) {
            float v = fmaxf(fmaxf(so[oc][pyl][pxl],     so[oc][pyl][pxl + 1]),
                            fmaxf(so[oc][pyl + 1][pxl], so[oc][pyl + 1][pxl + 1]));
            out[(size_t)b * ACT_STRIDE + ((size_t)oc * 61 + py) * 61 + px] = v;
        }
    }
}

// ================= fc1: split-K partials =================
#define FC1_K      55815
#define FC1_CHUNK  768
#define FC1_NC     73
#define FC1_RT     15

// grid (15, 73), block 256. Wave w owns rows rt*8 + {2w, 2w+1}.
__global__ __launch_bounds__(256) void fc1_partial_k(
    const float* __restrict__ act /*(10, ACT_STRIDE)*/,
    const float* __restrict__ w   /*(120, 55815)*/,
    float* __restrict__ partials  /*(73,120,10)*/) {
    int rt  = blockIdx.x;
    int c   = blockIdx.y;
    int tid = threadIdx.x;
    int wave = tid >> 6, lane = tid & 63;
    int k0 = c * FC1_CHUNK;
    int k1 = k0 + FC1_CHUNK; if (k1 > FC1_K) k1 = FC1_K;
    int r0 = rt * 8 + wave * 2;
    const float* w0 = w + (size_t)r0 * FC1_K;
    const float* w1 = w + (size_t)(r0 + 1) * FC1_K;

    float acc0[10], acc1[10];
    #pragma unroll
    for (int b = 0; b < 10; ++b) { acc0[b] = 0.f; acc1[b] = 0.f; }

    for (int k = k0 + lane * 4; k < k1; k += 256) {
        if (k + 4 <= k1) {
            float4 a4[10];
            #pragma unroll
            for (int b = 0; b < 10; ++b)
                a4[b] = *reinterpret_cast<const float4*>(act + (size_t)b * ACT_STRIDE + k);
            float w00 = w0[k], w01 = w0[k + 1], w02 = w0[k + 2], w03 = w0[k + 3];
            float w10 = w1[k], w11 = w1[k + 1], w12 = w1[k + 2], w13 = w1[k + 3];
            #pragma unroll
            for (int b = 0; b < 10; ++b) {
                acc0[b] += w00 * a4[b].x + w01 * a4[b].y + w02 * a4[b].z + w03 * a4[b].w;
                acc1[b] += w10 * a4[b].x + w11 * a4[b].y + w12 * a4[b].z + w13 * a4[b].w;
            }
        } else {
            for (int j = 0; j < k1 - k; ++j) {
                float wv0 = w0[k + j], wv1 = w1[k + j];
                #pragma unroll
                for (int b = 0; b < 10; ++b) {
                    float av = act[(size_t)b * ACT_STRIDE + k + j];
                    acc0[b] += wv0 * av;
                    acc1[b] += wv1 * av;
                }
            }
        }
    }
    #pragma unroll
    for (int b = 0; b < 10; ++b) {
        float v0 = acc0[b], v1 = acc1[b];
        for (int off = 32; off > 0; off >>= 1) {
            v0 += __shfl_down(v0, off);
            v1 += __shfl_down(v1, off);
        }
        if (lane == 0) {
            size_t base = ((size_t)c * 120 + r0) * 10;
            partials[base + b]      = v0;
            partials[base + 10 + b] = v1;
        }
    }
}

// ===== fcA: fc1-reduce + fc2 + fc3. grid 10 (one block per batch) x 128 =====
__global__ __launch_bounds__(128) void fcA_k(
    const float* __restrict__ part /*(73,120,10)*/, const float* __restrict__ fc1_b,
    const float* __restrict__ fc2_w, const float* __restrict__ fc2_b,
    const float* __restrict__ fc3_w, const float* __restrict__ fc3_b,
    float* __restrict__ h3 /*(10,)*/) {
    const int b = blockIdx.x;
    const int tid = threadIdx.x;
    __shared__ float s_act[120];
    __shared__ float s_fc2[84];

    if (tid < 120) {
        float s = 0.f;
        for (int c = 0; c < FC1_NC; ++c) s += part[((size_t)c * 120 + tid) * 10 + b];
        s_act[tid] = fmaxf(s + fc1_b[tid], 0.f);
    }
    __syncthreads();
    if (tid < 84) {
        float acc = fc2_b[tid];
        #pragma unroll 4
        for (int k = 0; k < 120; ++k) acc += s_act[k] * fc2_w[tid * 120 + k];
        s_fc2[tid] = fmaxf(acc, 0.f);
    }
    __syncthreads();
    if (tid < 64) {
        float v = s_fc2[tid] * fc3_w[tid];
        if (tid < 20) v += s_fc2[tid + 64] * fc3_w[tid + 64];
        for (int off = 32; off > 0; off >>= 1) v += __shfl_down(v, off);
        if (tid == 0) h3[b] = v + fc3_b[0];
    }
}

// ===== clsB: qnn (redundant per block) + RBF partials. 64 blocks x 128 =====
__global__ __launch_bounds__(128) void clsB_k(
    const float* __restrict__ h3 /*(10,)*/,
    const float* __restrict__ qw1, const float* __restrict__ qw2,
    const float* __restrict__ ts /*(8192,5)*/, const float* __restrict__ kw /*(2,8192)*/,
    float* __restrict__ partials /*(64,2)*/) {
    int tid = threadIdx.x;
    __shared__ float s_h3[10], s_s1[20], s_fs[5];
    if (tid < 10) s_h3[tid] = h3[tid];
    __syncthreads();
    if (tid < 20) {
        float acc = 0.f;
        for (int b = 0; b < 10; ++b) acc += qw1[tid * 10 + b] * s_h3[b];
        s_s1[tid] = tanhf(acc);
    }
    __syncthreads();
    if (tid < 5) {
        float acc = 0.f;
        for (int j = 0; j < 20; ++j) acc += qw2[tid * 20 + j] * s_s1[j];
        s_fs[tid] = tanhf(acc);
    }
    __syncthreads();

    float f0 = s_fs[0], f1 = s_fs[1], f2 = s_fs[2], f3 = s_fs[3], f4 = s_fs[4];
    int n = blockIdx.x * 128 + tid;
    const float* t = ts + (size_t)n * 5;
    float d0 = f0 - t[0], d1 = f1 - t[1], d2 = f2 - t[2], d3 = f3 - t[3], d4 = f4 - t[4];
    float Kv = expf(-(d0 * d0 + d1 * d1 + d2 * d2 + d3 * d3 + d4 * d4));
    float a0 = Kv * kw[n];
    float a1 = Kv * kw[8192 + n];
    for (int off = 32; off > 0; off >>= 1) {
        a0 += __shfl_down(a0, off);
        a1 += __shfl_down(a1, off);
    }
    __shared__ float l0[2], l1[2];
    int wave = tid >> 6, lane = tid & 63;
    if (lane == 0) { l0[wave] = a0; l1[wave] = a1; }
    __syncthreads();
    if (tid == 0) {
        partials[blockIdx.x * 2 + 0] = l0[0] + l0[1];
        partials[blockIdx.x * 2 + 1] = l1[0] + l1[1];
    }
}

__global__ void clsC_k(const float* __restrict__ partials,
                       const float* __restrict__ kb, float* __restrict__ out) {
    int c = threadIdx.x;
    if (c < 2) {
        float acc = kb[c];
        for (int i = 0; i < 64; ++i) acc += partials[i * 2 + c];
        out[c] = acc;
    }
}

extern "C" void kernel_launch(void* const* d_in, const int* in_sizes, int n_in,
                              void* d_out, int out_size, void* d_ws, size_t ws_size,
                              hipStream_t stream) {
    const float* x        = (const float*)d_in[0];
    const float* conv1_w  = (const float*)d_in[1];
    const float* conv1_b  = (const float*)d_in[2];
    const float* conv2_w  = (const float*)d_in[3];
    const float* conv2_b  = (const float*)d_in[4];
    const float* fc1_w    = (const float*)d_in[5];
    const float* fc1_b    = (const float*)d_in[6];
    const float* fc2_w    = (const float*)d_in[7];
    const float* fc2_b    = (const float*)d_in[8];
    const float* fc3_w    = (const float*)d_in[9];
    const float* fc3_b    = (const float*)d_in[10];
    const float* qnn_w1   = (const float*)d_in[11];
    const float* qnn_w2   = (const float*)d_in[12];
    const float* tstates  = (const float*)d_in[13];
    const float* kcls_w   = (const float*)d_in[14];
    const float* kcls_b   = (const float*)d_in[15];

    float* ws = (float*)d_ws;
    float* p1       = ws;                  // 10*6*123*123 = 907740
    float* p2       = p1 + 907740;         // 10*ACT_STRIDE = 558160 (16B-aligned)
    float* fc1_part = p2 + 558160;         // 73*120*10 = 87600
    float* h3       = fc1_part + 87600;    // 16
    float* partials = h3 + 16;             // 128

    convpool1_k<<<dim3(10, 31, 4), 256, 0, stream>>>(x, conv1_w, conv1_b, p1);
    convpool2_k<<<dim3(10, 31, 4), 128, 0, stream>>>(p1, conv2_w, conv2_b, p2);
    fc1_partial_k<<<dim3(FC1_RT, FC1_NC), 256, 0, stream>>>(p2, fc1_w, fc1_part);
    fcA_k<<<10, 128, 0, stream>>>(fc1_part, fc1_b, fc2_w, fc2_b, fc3_w, fc3_b, h3);
    clsB_k<<<64, 128, 0, stream>>>(h3, qnn_w1, qnn_w2, tstates, kcls_w, partials);
    clsC_k<<<1, 64, 0, stream>>>(partials, kcls_b, (float*)d_out);
}